// Round 16
// baseline (150.239 us; speedup 1.0000x reference)
//
#include <hip/hip_runtime.h>
#include <math.h>

#define D_IN  512
#define D_HID 64
#define D_OUT 40
#define CAP   64   // per-node edge capacity; deg ~ Poisson(16), max<<64

typedef __attribute__((ext_vector_type(8))) short bf16x8;
typedef __attribute__((ext_vector_type(4))) float f32x4;

static __device__ __forceinline__ unsigned short f2bf(float f) {
    unsigned u = __float_as_uint(f);
    return (unsigned short)((u + 0x7FFF + ((u >> 16) & 1)) >> 16);  // RNE
}
static __device__ __forceinline__ float bf2f(unsigned short h) {
    return __uint_as_float(((unsigned)h) << 16);
}

// ===========================================================================
// prep_all: zero cursor (N) | W1 -> w1T bf16 transposed | W2 -> w2T bf16
// ===========================================================================
__global__ __launch_bounds__(256)
void prep_all(int* __restrict__ cursor, const float* __restrict__ W1,
              unsigned short* __restrict__ w1T, const float* __restrict__ W2,
              unsigned short* __restrict__ w2T, int N) {
    const int i = blockIdx.x * blockDim.x + threadIdx.x;
    if (i < N) cursor[i] = 0;
    const int j = i - N;
    if (j >= 0 && j < D_IN * D_HID) {          // j = k*64 + col
        const int k = j >> 6, col = j & 63;
        w1T[col * D_IN + k] = f2bf(W1[j]);
    }
    const int l = j - D_IN * D_HID;
    if (l >= 0 && l < 48 * D_HID) {            // l = col*64 + k
        const int col = l >> 6, k = l & 63;
        w2T[l] = (col < D_OUT) ? f2bf(W2[k * D_OUT + col]) : 0;
    }
}

// ===========================================================================
// fat1: blocks [0, sBlocks) = capacity-CSR scatter (XCD-local, dispatched
// first so it overlaps gemm1); blocks [sBlocks, ...) = GEMM1 MFMA tiles.
//
// GEMM1 r15 post-mortem: BK=64 phases exposed ~900cy HBM latency 8x with
// only ~96 B/thread in flight -> 1.7 TB/s, 79 us. Now BK=256: 2 phases,
// each thread issues 24 independent loads (384 B) into register arrays
// BEFORE any convert/store -> ~200 KB/CU in flight, HBM-BW-bound.
// LDS 64 KB (xs 32K + ws 32K) -> 2 blocks/CU; fine for a BW-bound kernel.
// ===========================================================================
__global__ __launch_bounds__(256)
void fat1(const float* __restrict__ x, const unsigned short* __restrict__ w1T,
          const float* __restrict__ b1, unsigned short* __restrict__ h1,
          const int* __restrict__ src, const int* __restrict__ dstA,
          const float* __restrict__ wm, int* __restrict__ cursor,
          unsigned* __restrict__ edges, int E, int N, int sBlocks) {
    __shared__ unsigned char lds[65536];  // gemm1 role: xs @0 (64x512B), ws @32768 (64x512B)
    const int t = threadIdx.x;

    if ((int)blockIdx.x < sBlocks) {
        // ---------------- scatter: capacity-CSR, XCD-local ----------------
        const int slice = (N + 7) >> 3;
        const int lo = (blockIdx.x & 7) * slice;
        const int hi = min(N, lo + slice);
        const int nChunk = sBlocks >> 3;
        const int per = (E + nChunk - 1) / nChunk;
        const int beg = ((int)blockIdx.x >> 3) * per;
        const int end = min(E, beg + per);
        for (int e = beg + t; e < end; e += 256) {
            const int d = dstA[e];
            if (d >= lo && d < hi) {
                const int pos = atomicAdd(&cursor[d], 1);
                if (pos < CAP)
                    edges[(size_t)d * CAP + pos] =
                        ((unsigned)src[e] << 16) | (unsigned)f2bf(wm[e]);
            }
        }
        return;
    }

    // ---------------- GEMM1: h1[N,64] = x @ W1 + b1 ----------------
    const int lane = t & 63;
    const int wv = t >> 6;
    const int nodeBase = ((int)blockIdx.x - sBlocks) * 64;
    const int fr = lane & 15;
    const int fc = lane >> 4;

    f32x4 acc[4];
#pragma unroll
    for (int cg = 0; cg < 4; ++cg) acc[cg] = (f32x4){0.f, 0.f, 0.f, 0.f};

    for (int kbase = 0; kbase < D_IN; kbase += 256) {
        // ---- batched staging: ALL 24 loads issued before any convert/store
        float4 xa[8], xb[8];
        uint4  wr[8];
#pragma unroll
        for (int i = 0; i < 8; ++i) {
            const int G = t + i * 256;               // 0..2047
            const int row = G >> 5, g = G & 31;
            int gn = nodeBase + row; if (gn >= N) gn = N - 1;
            const float* sp = x + (size_t)gn * D_IN + kbase + g * 8;
            xa[i] = *reinterpret_cast<const float4*>(sp);
            xb[i] = *reinterpret_cast<const float4*>(sp + 4);
        }
#pragma unroll
        for (int i = 0; i < 8; ++i) {
            const int G = t + i * 256;
            const int col = G >> 5, g = G & 31;
            wr[i] = *reinterpret_cast<const uint4*>(w1T + (size_t)col * D_IN + kbase + g * 8);
        }
        if (kbase) __syncthreads();  // previous chunk's MFMA reads done
#pragma unroll
        for (int i = 0; i < 8; ++i) {
            const int G = t + i * 256;
            const int row = G >> 5, g = G & 31;
            uint4 p;
            p.x = (unsigned)f2bf(xa[i].x) | ((unsigned)f2bf(xa[i].y) << 16);
            p.y = (unsigned)f2bf(xa[i].z) | ((unsigned)f2bf(xa[i].w) << 16);
            p.z = (unsigned)f2bf(xb[i].x) | ((unsigned)f2bf(xb[i].y) << 16);
            p.w = (unsigned)f2bf(xb[i].z) | ((unsigned)f2bf(xb[i].w) << 16);
            *reinterpret_cast<uint4*>(lds + row * 512 + ((g * 16) ^ ((row & 7) << 4))) = p;
        }
#pragma unroll
        for (int i = 0; i < 8; ++i) {
            const int G = t + i * 256;
            const int col = G >> 5, g = G & 31;
            *reinterpret_cast<uint4*>(lds + 32768 + col * 512 + ((g * 16) ^ ((col & 7) << 4))) = wr[i];
        }
        __syncthreads();

        // ---- MFMA: 8 k-steps of 32 over this 256-k chunk
#pragma unroll
        for (int s = 0; s < 8; ++s) {
            const int g = s * 4 + fc;
            const int arow = wv * 16 + fr;
            const bf16x8 afrag = *reinterpret_cast<const bf16x8*>(
                lds + arow * 512 + ((g * 16) ^ ((arow & 7) << 4)));
#pragma unroll
            for (int cg = 0; cg < 4; ++cg) {
                const int brow = cg * 16 + fr;
                const bf16x8 bfrag = *reinterpret_cast<const bf16x8*>(
                    lds + 32768 + brow * 512 + ((g * 16) ^ ((brow & 7) << 4)));
                acc[cg] = __builtin_amdgcn_mfma_f32_16x16x32_bf16(afrag, bfrag, acc[cg], 0, 0, 0);
            }
        }
    }

    const int rq = lane >> 4;
#pragma unroll
    for (int cg = 0; cg < 4; ++cg) {
        const int col = cg * 16 + fr;
        const float bb = b1[col];
#pragma unroll
        for (int r = 0; r < 4; ++r) {
            const int node = nodeBase + wv * 16 + rq * 4 + r;
            if (node < N)
                h1[(size_t)node * D_HID + col] = f2bf(acc[cg][r] + bb);
        }
    }
}

// ===========================================================================
// Aggregation 1 (64 ch): wave/node, lane=channel. XCD-aligned node mapping
// (slice = bid%8 matches scatter's XCD-local writes). 8-deep gathers,
// fused relu + bf16 store.
// ===========================================================================
__global__ __launch_bounds__(256)
void agg_hid(const unsigned short* __restrict__ h, const unsigned* __restrict__ edges,
             const int* __restrict__ count, unsigned short* __restrict__ agg1, int N) {
    const int lane = threadIdx.x & 63;
    const int wv   = (threadIdx.x >> 6);
    const int slice = (N + 7) >> 3;                       // 6250
    const int local = ((int)blockIdx.x >> 3) * 4 + wv;    // node within slice
    if (local >= slice) return;
    const int n = ((int)blockIdx.x & 7) * slice + local;
    if (n >= N) return;
    const unsigned er = edges[(size_t)n * CAP + lane];
    const int cnt = min(count[n], CAP);
    float acc = 0.f;
    int j = 0;
    for (; j + 8 <= cnt; j += 8) {
        unsigned p[8];
#pragma unroll
        for (int u = 0; u < 8; ++u) p[u] = (unsigned)__shfl((int)er, j + u);
        float v[8];
#pragma unroll
        for (int u = 0; u < 8; ++u) v[u] = bf2f(h[(size_t)(p[u] >> 16) * D_HID + lane]);
#pragma unroll
        for (int u = 0; u < 8; ++u)
            acc += bf2f((unsigned short)(p[u] & 0xffff)) * v[u];
    }
    for (; j < cnt; ++j) {
        const unsigned p0 = (unsigned)__shfl((int)er, j);
        acc += bf2f((unsigned short)(p0 & 0xffff)) *
               bf2f(h[(size_t)(p0 >> 16) * D_HID + lane]);
    }
    agg1[(size_t)n * D_HID + lane] = f2bf(fmaxf(acc, 0.f));  // fused relu
}

// ===========================================================================
// GEMM2 (MFMA bf16): h2[N,40](bf16) = agg1relu[N,64] @ W2 + b2
// ===========================================================================
__global__ __launch_bounds__(256)
void gemm2_mfma(const unsigned short* __restrict__ agg1,
                const unsigned short* __restrict__ w2T,
                const float* __restrict__ b2, unsigned short* __restrict__ h2, int N) {
    __shared__ unsigned char lds[8192 + 6144];  // A @0 (64x128B), B @8192 (48x128B)
    const int t = threadIdx.x;
    const int lane = t & 63;
    const int wv = t >> 6;
    const int nodeBase = blockIdx.x * 64;

#pragma unroll
    for (int hh = 0; hh < 2; ++hh) {
        const int g = t + hh * 256;
        const int row = g >> 3, slot = g & 7;
        int gn = nodeBase + row; if (gn >= N) gn = N - 1;
        const uint4 p = *reinterpret_cast<const uint4*>(agg1 + (size_t)gn * D_HID + slot * 8);
        *reinterpret_cast<uint4*>(lds + row * 128 + ((slot << 4) ^ ((row & 7) << 4))) = p;
    }
    for (int g = t; g < 384; g += 256) {
        const int row = g >> 3, slot = g & 7;
        const uint4 p = *reinterpret_cast<const uint4*>(w2T + (size_t)row * D_HID + slot * 8);
        *reinterpret_cast<uint4*>(lds + 8192 + row * 128 + ((slot << 4) ^ ((row & 7) << 4))) = p;
    }
    __syncthreads();

    f32x4 acc[3];
#pragma unroll
    for (int cg = 0; cg < 3; ++cg) acc[cg] = (f32x4){0.f, 0.f, 0.f, 0.f};

    const int fr = lane & 15;
    const int fc = lane >> 4;
#pragma unroll
    for (int s = 0; s < 2; ++s) {
        const int slot = s * 4 + fc;
        const int arow = wv * 16 + fr;
        const bf16x8 afrag = *reinterpret_cast<const bf16x8*>(
            lds + arow * 128 + ((slot << 4) ^ ((arow & 7) << 4)));
#pragma unroll
        for (int cg = 0; cg < 3; ++cg) {
            const int brow = cg * 16 + fr;
            const bf16x8 bfrag = *reinterpret_cast<const bf16x8*>(
                lds + 8192 + brow * 128 + ((slot << 4) ^ ((brow & 7) << 4)));
            acc[cg] = __builtin_amdgcn_mfma_f32_16x16x32_bf16(afrag, bfrag, acc[cg], 0, 0, 0);
        }
    }

    const int rq = lane >> 4;
#pragma unroll
    for (int cg = 0; cg < 3; ++cg) {
        const int col = cg * 16 + fr;
        if (col < D_OUT) {
            const float bb = b2[col];
#pragma unroll
            for (int r = 0; r < 4; ++r) {
                const int node = nodeBase + wv * 16 + rq * 4 + r;
                if (node < N)
                    h2[(size_t)node * D_OUT + col] = f2bf(acc[cg][r] + bb);
            }
        }
    }
}

// ===========================================================================
// Aggregation 2 (40 ch) + log_softmax. XCD-aligned node mapping, 8-deep.
// ===========================================================================
__global__ __launch_bounds__(256)
void agg40_lsm(const unsigned short* __restrict__ h2, const unsigned* __restrict__ edges,
               const int* __restrict__ count, float* __restrict__ out, int N) {
    const int lane = threadIdx.x & 63;
    const int col  = (lane < D_OUT) ? lane : 0;  // clamped gather, no branch
    const int wv   = (threadIdx.x >> 6);
    const int slice = (N + 7) >> 3;
    const int local = ((int)blockIdx.x >> 3) * 4 + wv;
    if (local >= slice) return;
    const int n = ((int)blockIdx.x & 7) * slice + local;
    if (n >= N) return;
    const unsigned er = edges[(size_t)n * CAP + lane];
    const int cnt = min(count[n], CAP);
    float acc = 0.f;
    int j = 0;
    for (; j + 8 <= cnt; j += 8) {
        unsigned p[8];
#pragma unroll
        for (int u = 0; u < 8; ++u) p[u] = (unsigned)__shfl((int)er, j + u);
        float v[8];
#pragma unroll
        for (int u = 0; u < 8; ++u) v[u] = bf2f(h2[(size_t)(p[u] >> 16) * D_OUT + col]);
#pragma unroll
        for (int u = 0; u < 8; ++u)
            acc += bf2f((unsigned short)(p[u] & 0xffff)) * v[u];
    }
    for (; j < cnt; ++j) {
        const unsigned p0 = (unsigned)__shfl((int)er, j);
        acc += bf2f((unsigned short)(p0 & 0xffff)) *
               bf2f(h2[(size_t)(p0 >> 16) * D_OUT + col]);
    }
    const float v = (lane < D_OUT) ? acc : -INFINITY;
    float m = v;
#pragma unroll
    for (int o = 32; o > 0; o >>= 1) m = fmaxf(m, __shfl_xor(m, o, 64));
    float s = (lane < D_OUT) ? __expf(v - m) : 0.f;
#pragma unroll
    for (int o = 32; o > 0; o >>= 1) s += __shfl_xor(s, o, 64);
    if (lane < D_OUT) out[(size_t)n * D_OUT + lane] = v - m - __logf(s);
}

// ===========================================================================
extern "C" void kernel_launch(void* const* d_in, const int* in_sizes, int n_in,
                              void* d_out, int out_size, void* d_ws, size_t ws_size,
                              hipStream_t stream) {
    const float* x   = (const float*)d_in[0];
    const int*   ei  = (const int*)d_in[1];
    const float* wm  = (const float*)d_in[2];
    const float* W1  = (const float*)d_in[3];
    const float* b1  = (const float*)d_in[4];
    const float* W2  = (const float*)d_in[5];
    const float* b2  = (const float*)d_in[6];

    const int N = in_sizes[0] / D_IN;   // 50000
    const int E = in_sizes[2];          // 800000
    const int* srcIdx = ei;
    const int* dstIdx = ei + E;

    // workspace layout (16B-aligned blocks)
    unsigned short* w1T    = (unsigned short*)d_ws;                   // 64 KiB
    unsigned short* h1bf   = w1T + (size_t)D_HID * D_IN;              // N*64 bf16
    unsigned short* agg1bf = h1bf + (size_t)N * D_HID;                // N*64 bf16 (relu'd)
    unsigned* edges        = (unsigned*)(agg1bf + (size_t)N * D_HID); // N*CAP u32
    int*   cursor          = (int*)(edges + (size_t)N * CAP);         // N (= counts)
    unsigned short* w2T    = (unsigned short*)(cursor + N);           // 48*64 bf16
    unsigned short* h2bf   = h1bf;                                    // reuse (h1 dead after agg_hid)
    float* out             = (float*)d_out;

    const int g1Blocks = (N + 63) / 64;          // 782
    const int sBlocks  = 1024;                   // 128 chunks x 8 XCD slices
    const int prepWork = N + D_IN * D_HID + 48 * D_HID;
    const int slice = (N + 7) >> 3;              // 6250
    const int aggBlocks = ((slice + 3) / 4) * 8; // XCD-aligned agg grid

    prep_all<<<(prepWork + 255) / 256, 256, 0, stream>>>(cursor, W1, w1T, W2, w2T, N);
    fat1<<<sBlocks + g1Blocks, 256, 0, stream>>>(
        x, w1T, b1, h1bf, srcIdx, dstIdx, wm, cursor, edges, E, N, sBlocks);
    agg_hid<<<aggBlocks, 256, 0, stream>>>(h1bf, edges, cursor, agg1bf, N);
    gemm2_mfma<<<g1Blocks, 256, 0, stream>>>(agg1bf, w2T, b2, h2bf, N);
    agg40_lsm<<<aggBlocks, 256, 0, stream>>>(h2bf, edges, cursor, out, N);
}

// Round 17
// 123.978 us; speedup vs baseline: 1.2118x; 1.2118x over previous
//
#include <hip/hip_runtime.h>
#include <math.h>

#define D_IN  512
#define D_HID 64
#define D_OUT 40
#define CAP   64   // per-node edge capacity; deg ~ Poisson(16), max<<64

typedef __attribute__((ext_vector_type(8))) short bf16x8;
typedef __attribute__((ext_vector_type(4))) float f32x4;

static __device__ __forceinline__ unsigned short f2bf(float f) {
    unsigned u = __float_as_uint(f);
    return (unsigned short)((u + 0x7FFF + ((u >> 16) & 1)) >> 16);  // RNE
}
static __device__ __forceinline__ float bf2f(unsigned short h) {
    return __uint_as_float(((unsigned)h) << 16);
}

// ===========================================================================
// prep_all: zero cursor (N) | W1 -> w1T bf16 transposed | W2 -> w2T bf16
// ===========================================================================
__global__ __launch_bounds__(256)
void prep_all(int* __restrict__ cursor, const float* __restrict__ W1,
              unsigned short* __restrict__ w1T, const float* __restrict__ W2,
              unsigned short* __restrict__ w2T, int N) {
    const int i = blockIdx.x * blockDim.x + threadIdx.x;
    if (i < N) cursor[i] = 0;
    const int j = i - N;
    if (j >= 0 && j < D_IN * D_HID) {          // j = k*64 + col
        const int k = j >> 6, col = j & 63;
        w1T[col * D_IN + k] = f2bf(W1[j]);
    }
    const int l = j - D_IN * D_HID;
    if (l >= 0 && l < 48 * D_HID) {            // l = col*64 + k
        const int col = l >> 6, k = l & 63;
        w2T[l] = (col < D_OUT) ? f2bf(W2[k * D_OUT + col]) : 0;
    }
}

// ===========================================================================
// fat1: blocks [0, sBlocks) = capacity-CSR scatter (XCD-local, dispatched
// first); blocks [sBlocks, ...) = GEMM1 MFMA tiles.
//
// GEMM1 r16 post-mortem: register-array staging (384 B/thread) SPILLED
// (VGPR 88, 78 MB scratch writes). Now: zero-VGPR staging via
// __builtin_amdgcn_global_load_lds width=16. x stays fp32 in LDS
// (converted at fragment read); swizzle achieved by pre-swizzled PER-LANE
// global source + linear LDS dest (rule 21). 24.6 KB LDS -> 6 blocks/CU,
// ~144 KB DMA in flight per CU (m97's implicit-overlap regime).
// ===========================================================================
__global__ __launch_bounds__(256)
void fat1(const float* __restrict__ x, const unsigned short* __restrict__ w1T,
          const float* __restrict__ b1, unsigned short* __restrict__ h1,
          const int* __restrict__ src, const int* __restrict__ dstA,
          const float* __restrict__ wm, int* __restrict__ cursor,
          unsigned* __restrict__ edges, int E, int N, int sBlocks) {
    __shared__ unsigned char lds[24576];  // xs fp32 @0 (64x256B), ws bf16 @16384 (64x128B)
    const int t = threadIdx.x;

    if ((int)blockIdx.x < sBlocks) {
        // ---------------- scatter: capacity-CSR, XCD-local ----------------
        const int slice = (N + 7) >> 3;
        const int lo = (blockIdx.x & 7) * slice;
        const int hi = min(N, lo + slice);
        const int nChunk = sBlocks >> 3;
        const int per = (E + nChunk - 1) / nChunk;
        const int beg = ((int)blockIdx.x >> 3) * per;
        const int end = min(E, beg + per);
        for (int e = beg + t; e < end; e += 256) {
            const int d = dstA[e];
            if (d >= lo && d < hi) {
                const int pos = atomicAdd(&cursor[d], 1);
                if (pos < CAP)
                    edges[(size_t)d * CAP + pos] =
                        ((unsigned)src[e] << 16) | (unsigned)f2bf(wm[e]);
            }
        }
        return;
    }

    // ---------------- GEMM1: h1[N,64] = x @ W1 + b1 ----------------
    const int lane = t & 63;
    const int wv = t >> 6;
    const int nodeBase = ((int)blockIdx.x - sBlocks) * 64;
    const int fr = lane & 15;
    const int fc = lane >> 4;

    f32x4 acc[4];
#pragma unroll
    for (int cg = 0; cg < 4; ++cg) acc[cg] = (f32x4){0.f, 0.f, 0.f, 0.f};

    for (int c = 0; c < 8; ++c) {   // 8 chunks of 64 k
        if (c) __syncthreads();     // previous chunk's LDS reads complete

        // ---- x tile: 16 KB fp32, 16 DMA instrs (4/wave). Lane l of instr
        // lands at instr*1024 + l*16 (linear); per-lane SOURCE granule is
        // pre-swizzled: (l&15)^(row&7), so reads use the 16B-XOR layout.
#pragma unroll
        for (int i = 0; i < 4; ++i) {
            const int instr = wv * 4 + i;                 // 0..15 (wave-uniform)
            const int row = instr * 4 + (lane >> 4);
            int gn = nodeBase + row; if (gn >= N) gn = N - 1;
            const int gran = (lane & 15) ^ (row & 7);     // 16B granule of this row-chunk
            const float* gp = x + (size_t)gn * D_IN + c * 64 + gran * 4;
            __builtin_amdgcn_global_load_lds(
                (const __attribute__((address_space(1))) void*)gp,
                (__attribute__((address_space(3))) void*)(lds + instr * 1024),
                16, 0, 0);
        }
        // ---- W tile: 8 KB bf16, 8 DMA instrs (2/wave), same swizzle family
#pragma unroll
        for (int i = 0; i < 2; ++i) {
            const int instr = wv * 2 + i;                 // 0..7
            const int col = instr * 8 + (lane >> 3);
            const int gsl = (lane & 7) ^ (col & 7);
            const unsigned short* gp = w1T + (size_t)col * D_IN + c * 64 + gsl * 8;
            __builtin_amdgcn_global_load_lds(
                (const __attribute__((address_space(1))) void*)gp,
                (__attribute__((address_space(3))) void*)(lds + 16384 + instr * 1024),
                16, 0, 0);
        }
        __syncthreads();  // drains vmcnt -> tiles ready

        // ---- MFMA: 2 k-steps of 32; A converted fp32->bf16 at read
#pragma unroll
        for (int s = 0; s < 2; ++s) {
            const int arow = wv * 16 + fr;
            const int g0 = (s * 8 + fc * 2) ^ (arow & 7);     // 16B granules of fp32 row
            const int g1 = (s * 8 + fc * 2 + 1) ^ (arow & 7);
            const f32x4 a0 = *reinterpret_cast<const f32x4*>(lds + arow * 256 + (g0 << 4));
            const f32x4 a1 = *reinterpret_cast<const f32x4*>(lds + arow * 256 + (g1 << 4));
            uint4 pk;
            pk.x = (unsigned)f2bf(a0[0]) | ((unsigned)f2bf(a0[1]) << 16);
            pk.y = (unsigned)f2bf(a0[2]) | ((unsigned)f2bf(a0[3]) << 16);
            pk.z = (unsigned)f2bf(a1[0]) | ((unsigned)f2bf(a1[1]) << 16);
            pk.w = (unsigned)f2bf(a1[2]) | ((unsigned)f2bf(a1[3]) << 16);
            const bf16x8 afrag = *reinterpret_cast<const bf16x8*>(&pk);
            const int slot = s * 4 + fc;
#pragma unroll
            for (int cg = 0; cg < 4; ++cg) {
                const int brow = cg * 16 + fr;
                const bf16x8 bfrag = *reinterpret_cast<const bf16x8*>(
                    lds + 16384 + brow * 128 + (((slot ^ (brow & 7))) << 4));
                acc[cg] = __builtin_amdgcn_mfma_f32_16x16x32_bf16(afrag, bfrag, acc[cg], 0, 0, 0);
            }
        }
    }

    const int rq = lane >> 4;
#pragma unroll
    for (int cg = 0; cg < 4; ++cg) {
        const int col = cg * 16 + fr;
        const float bb = b1[col];
#pragma unroll
        for (int r = 0; r < 4; ++r) {
            const int node = nodeBase + wv * 16 + rq * 4 + r;
            if (node < N)
                h1[(size_t)node * D_HID + col] = f2bf(acc[cg][r] + bb);
        }
    }
}

// ===========================================================================
// Aggregation 1 (64 ch): wave/node, lane=channel. XCD-aligned node mapping
// (slice = bid%8 matches scatter's XCD-local writes). 8-deep gathers,
// fused relu + bf16 store.
// ===========================================================================
__global__ __launch_bounds__(256)
void agg_hid(const unsigned short* __restrict__ h, const unsigned* __restrict__ edges,
             const int* __restrict__ count, unsigned short* __restrict__ agg1, int N) {
    const int lane = threadIdx.x & 63;
    const int wv   = (threadIdx.x >> 6);
    const int slice = (N + 7) >> 3;                       // 6250
    const int local = ((int)blockIdx.x >> 3) * 4 + wv;    // node within slice
    if (local >= slice) return;
    const int n = ((int)blockIdx.x & 7) * slice + local;
    if (n >= N) return;
    const unsigned er = edges[(size_t)n * CAP + lane];
    const int cnt = min(count[n], CAP);
    float acc = 0.f;
    int j = 0;
    for (; j + 8 <= cnt; j += 8) {
        unsigned p[8];
#pragma unroll
        for (int u = 0; u < 8; ++u) p[u] = (unsigned)__shfl((int)er, j + u);
        float v[8];
#pragma unroll
        for (int u = 0; u < 8; ++u) v[u] = bf2f(h[(size_t)(p[u] >> 16) * D_HID + lane]);
#pragma unroll
        for (int u = 0; u < 8; ++u)
            acc += bf2f((unsigned short)(p[u] & 0xffff)) * v[u];
    }
    for (; j < cnt; ++j) {
        const unsigned p0 = (unsigned)__shfl((int)er, j);
        acc += bf2f((unsigned short)(p0 & 0xffff)) *
               bf2f(h[(size_t)(p0 >> 16) * D_HID + lane]);
    }
    agg1[(size_t)n * D_HID + lane] = f2bf(fmaxf(acc, 0.f));  // fused relu
}

// ===========================================================================
// GEMM2 (MFMA bf16): h2[N,40](bf16) = agg1relu[N,64] @ W2 + b2
// ===========================================================================
__global__ __launch_bounds__(256)
void gemm2_mfma(const unsigned short* __restrict__ agg1,
                const unsigned short* __restrict__ w2T,
                const float* __restrict__ b2, unsigned short* __restrict__ h2, int N) {
    __shared__ unsigned char lds[8192 + 6144];  // A @0 (64x128B), B @8192 (48x128B)
    const int t = threadIdx.x;
    const int lane = t & 63;
    const int wv = t >> 6;
    const int nodeBase = blockIdx.x * 64;

#pragma unroll
    for (int hh = 0; hh < 2; ++hh) {
        const int g = t + hh * 256;
        const int row = g >> 3, slot = g & 7;
        int gn = nodeBase + row; if (gn >= N) gn = N - 1;
        const uint4 p = *reinterpret_cast<const uint4*>(agg1 + (size_t)gn * D_HID + slot * 8);
        *reinterpret_cast<uint4*>(lds + row * 128 + ((slot << 4) ^ ((row & 7) << 4))) = p;
    }
    for (int g = t; g < 384; g += 256) {
        const int row = g >> 3, slot = g & 7;
        const uint4 p = *reinterpret_cast<const uint4*>(w2T + (size_t)row * D_HID + slot * 8);
        *reinterpret_cast<uint4*>(lds + 8192 + row * 128 + ((slot << 4) ^ ((row & 7) << 4))) = p;
    }
    __syncthreads();

    f32x4 acc[3];
#pragma unroll
    for (int cg = 0; cg < 3; ++cg) acc[cg] = (f32x4){0.f, 0.f, 0.f, 0.f};

    const int fr = lane & 15;
    const int fc = lane >> 4;
#pragma unroll
    for (int s = 0; s < 2; ++s) {
        const int slot = s * 4 + fc;
        const int arow = wv * 16 + fr;
        const bf16x8 afrag = *reinterpret_cast<const bf16x8*>(
            lds + arow * 128 + ((slot << 4) ^ ((arow & 7) << 4)));
#pragma unroll
        for (int cg = 0; cg < 3; ++cg) {
            const int brow = cg * 16 + fr;
            const bf16x8 bfrag = *reinterpret_cast<const bf16x8*>(
                lds + 8192 + brow * 128 + ((slot << 4) ^ ((brow & 7) << 4)));
            acc[cg] = __builtin_amdgcn_mfma_f32_16x16x32_bf16(afrag, bfrag, acc[cg], 0, 0, 0);
        }
    }

    const int rq = lane >> 4;
#pragma unroll
    for (int cg = 0; cg < 3; ++cg) {
        const int col = cg * 16 + fr;
        if (col < D_OUT) {
            const float bb = b2[col];
#pragma unroll
            for (int r = 0; r < 4; ++r) {
                const int node = nodeBase + wv * 16 + rq * 4 + r;
                if (node < N)
                    h2[(size_t)node * D_OUT + col] = f2bf(acc[cg][r] + bb);
            }
        }
    }
}

// ===========================================================================
// Aggregation 2 (40 ch) + log_softmax. XCD-aligned node mapping, 8-deep.
// ===========================================================================
__global__ __launch_bounds__(256)
void agg40_lsm(const unsigned short* __restrict__ h2, const unsigned* __restrict__ edges,
               const int* __restrict__ count, float* __restrict__ out, int N) {
    const int lane = threadIdx.x & 63;
    const int col  = (lane < D_OUT) ? lane : 0;  // clamped gather, no branch
    const int wv   = (threadIdx.x >> 6);
    const int slice = (N + 7) >> 3;
    const int local = ((int)blockIdx.x >> 3) * 4 + wv;
    if (local >= slice) return;
    const int n = ((int)blockIdx.x & 7) * slice + local;
    if (n >= N) return;
    const unsigned er = edges[(size_t)n * CAP + lane];
    const int cnt = min(count[n], CAP);
    float acc = 0.f;
    int j = 0;
    for (; j + 8 <= cnt; j += 8) {
        unsigned p[8];
#pragma unroll
        for (int u = 0; u < 8; ++u) p[u] = (unsigned)__shfl((int)er, j + u);
        float v[8];
#pragma unroll
        for (int u = 0; u < 8; ++u) v[u] = bf2f(h2[(size_t)(p[u] >> 16) * D_OUT + col]);
#pragma unroll
        for (int u = 0; u < 8; ++u)
            acc += bf2f((unsigned short)(p[u] & 0xffff)) * v[u];
    }
    for (; j < cnt; ++j) {
        const unsigned p0 = (unsigned)__shfl((int)er, j);
        acc += bf2f((unsigned short)(p0 & 0xffff)) *
               bf2f(h2[(size_t)(p0 >> 16) * D_OUT + col]);
    }
    const float v = (lane < D_OUT) ? acc : -INFINITY;
    float m = v;
#pragma unroll
    for (int o = 32; o > 0; o >>= 1) m = fmaxf(m, __shfl_xor(m, o, 64));
    float s = (lane < D_OUT) ? __expf(v - m) : 0.f;
#pragma unroll
    for (int o = 32; o > 0; o >>= 1) s += __shfl_xor(s, o, 64);
    if (lane < D_OUT) out[(size_t)n * D_OUT + lane] = v - m - __logf(s);
}

// ===========================================================================
extern "C" void kernel_launch(void* const* d_in, const int* in_sizes, int n_in,
                              void* d_out, int out_size, void* d_ws, size_t ws_size,
                              hipStream_t stream) {
    const float* x   = (const float*)d_in[0];
    const int*   ei  = (const int*)d_in[1];
    const float* wm  = (const float*)d_in[2];
    const float* W1  = (const float*)d_in[3];
    const float* b1  = (const float*)d_in[4];
    const float* W2  = (const float*)d_in[5];
    const float* b2  = (const float*)d_in[6];

    const int N = in_sizes[0] / D_IN;   // 50000
    const int E = in_sizes[2];          // 800000
    const int* srcIdx = ei;
    const int* dstIdx = ei + E;

    // workspace layout (16B-aligned blocks)
    unsigned short* w1T    = (unsigned short*)d_ws;                   // 64 KiB
    unsigned short* h1bf   = w1T + (size_t)D_HID * D_IN;              // N*64 bf16
    unsigned short* agg1bf = h1bf + (size_t)N * D_HID;                // N*64 bf16 (relu'd)
    unsigned* edges        = (unsigned*)(agg1bf + (size_t)N * D_HID); // N*CAP u32
    int*   cursor          = (int*)(edges + (size_t)N * CAP);         // N (= counts)
    unsigned short* w2T    = (unsigned short*)(cursor + N);           // 48*64 bf16
    unsigned short* h2bf   = h1bf;                                    // reuse (h1 dead after agg_hid)
    float* out             = (float*)d_out;

    const int g1Blocks = (N + 63) / 64;          // 782
    const int sBlocks  = 1024;                   // 128 chunks x 8 XCD slices
    const int prepWork = N + D_IN * D_HID + 48 * D_HID;
    const int slice = (N + 7) >> 3;              // 6250
    const int aggBlocks = ((slice + 3) / 4) * 8; // XCD-aligned agg grid

    prep_all<<<(prepWork + 255) / 256, 256, 0, stream>>>(cursor, W1, w1T, W2, w2T, N);
    fat1<<<sBlocks + g1Blocks, 256, 0, stream>>>(
        x, w1T, b1, h1bf, srcIdx, dstIdx, wm, cursor, edges, E, N, sBlocks);
    agg_hid<<<aggBlocks, 256, 0, stream>>>(h1bf, edges, cursor, agg1bf, N);
    gemm2_mfma<<<g1Blocks, 256, 0, stream>>>(agg1bf, w2T, b2, h2bf, N);
    agg40_lsm<<<aggBlocks, 256, 0, stream>>>(h2bf, edges, cursor, out, N);
}